// Round 6
// baseline (358.571 us; speedup 1.0000x reference)
//
#include <hip/hip_runtime.h>
#include <stdint.h>

#define B   256
#define IU  8      // in_units (i)
#define JC  1152   // in_channels (j)
#define NN  10     // num_units (n)
#define UU  16     // unit_size (u)
#define NU  160    // NN*UU
#define JN  11520  // JC*NN
#define WROW 1280  // NN*UU*IU, floats per j in W

// ---- fused: blog += db/B; c = softmax_j(blog); db = 0 -------------------
__global__ void k_softmax_upd(float* __restrict__ blog, float* __restrict__ db,
                              float* __restrict__ c) {
    int n = blockIdx.x;           // 0..9
    int tid = threadIdx.x;        // 256
    float myv[5]; int cnt = 0;
    for (int j = tid; j < JC; j += 256) {
        float val = blog[j*NN + n] + db[j*NN + n] * (1.f / (float)B);
        blog[j*NN + n] = val;
        db[j*NN + n] = 0.f;       // self-zero for next k_uhat_db
        myv[cnt++] = val;
    }
    __shared__ float red[256];
    float m = -1e30f;
    for (int k = 0; k < cnt; ++k) m = fmaxf(m, myv[k]);
    red[tid] = m; __syncthreads();
    for (int s = 128; s > 0; s >>= 1) {
        if (tid < s) red[tid] = fmaxf(red[tid], red[tid+s]);
        __syncthreads();
    }
    m = red[0]; __syncthreads();
    float sum = 0.f;
    for (int k = 0; k < cnt; ++k) sum += __expf(myv[k] - m);
    red[tid] = sum; __syncthreads();
    for (int s = 128; s > 0; s >>= 1) {
        if (tid < s) red[tid] += red[tid+s];
        __syncthreads();
    }
    float inv = 1.f / red[0];
    cnt = 0;
    for (int j = tid; j < JC; j += 256)
        c[j*NN + n] = __expf(myv[cnt++] - m) * inv;
}

// ---------------- heavy pass 1: sbuf[b][n*16+u] += c*u_hat (atomic) -------
// grid (36 j-tiles of 32, 32 b-tiles of 8), block 320 (1152 blocks).
// js = tid&7 (j-split, lane bits 0..2), g = tid>>3 (0..39): n = g>>2, uq = g&3.
// cptr == nullptr on iter 0 -> c = 1/JC exactly (softmax of zeros).
__global__ void __launch_bounds__(320, 4)
k_uhat_s(const float* __restrict__ xg, const float* __restrict__ wg,
         const float* __restrict__ cptr, float* __restrict__ sbuf) {
    const int jt = blockIdx.x, bt = blockIdx.y;
    const int j0 = jt * 32, b0 = bt * 8;
    const int tid = threadIdx.x;
    const int js = tid & 7;
    const int g  = tid >> 3;       // 0..39
    const int n  = g >> 2;
    const int uq = g & 3;

    __shared__ float xs[32 * 68];  // xs[jl*68 + b*8 + i]
    __shared__ float cs[320];      // cs[jl*10 + n]

    for (int idx = tid; idx < 2048; idx += 320) {
        int jl = idx & 31;
        int r  = idx >> 5;
        int i  = r & 7;
        int b  = r >> 3;
        xs[jl*68 + b*8 + i] = xg[(size_t)(b0 + b) * (IU*JC) + i * JC + j0 + jl];
    }
    if (cptr && tid < 320) cs[tid] = cptr[j0*NN + tid];
    __syncthreads();

    float acc[32];                 // acc[bb*4 + u]
    #pragma unroll
    for (int k = 0; k < 32; ++k) acc[k] = 0.f;

    #pragma unroll
    for (int jj = 0; jj < 4; ++jj) {
        const int jl = jj*8 + js;
        const int j  = j0 + jl;
        const float cc = cptr ? cs[jl*NN + n] : (1.0f / (float)JC);
        const float4* wp = reinterpret_cast<const float4*>(
            wg + (size_t)j * WROW + n * (UU*IU) + uq * 32);
        float wf[32];              // wf[u*8 + i], u = 0..3 (within quarter)
        #pragma unroll
        for (int r = 0; r < 8; ++r) {
            float4 wv = wp[r];
            wf[r*4+0] = wv.x * cc; wf[r*4+1] = wv.y * cc;
            wf[r*4+2] = wv.z * cc; wf[r*4+3] = wv.w * cc;
        }
        #pragma unroll
        for (int bb = 0; bb < 8; ++bb) {
            const float4* xp = reinterpret_cast<const float4*>(&xs[jl*68 + bb*8]);
            float4 x0 = xp[0], x1 = xp[1];
            #pragma unroll
            for (int u = 0; u < 4; ++u) {
                const float* w8 = &wf[u*8];
                float a = acc[bb*4 + u];
                a = fmaf(w8[0], x0.x, a); a = fmaf(w8[1], x0.y, a);
                a = fmaf(w8[2], x0.z, a); a = fmaf(w8[3], x0.w, a);
                a = fmaf(w8[4], x1.x, a); a = fmaf(w8[5], x1.y, a);
                a = fmaf(w8[6], x1.z, a); a = fmaf(w8[7], x1.w, a);
                acc[bb*4 + u] = a;
            }
        }
    }

    // butterfly over the 8 j-split lanes (lane bits 0..2)
    #pragma unroll
    for (int k = 0; k < 32; ++k) {
        float a = acc[k];
        a += __shfl_xor(a, 4);
        a += __shfl_xor(a, 2);
        a += __shfl_xor(a, 1);
        acc[k] = a;
    }
    // lane js commits batch bb == js (4 u-values)
    #pragma unroll
    for (int u = 0; u < 4; ++u)
        atomicAdd(&sbuf[(size_t)(b0 + js) * NU + n*16 + uq*4 + u], acc[js*4 + u]);
}

// ---------------- squash: vdst[b][t] = squash(sbuf)[b][t]; sbuf = 0 ------
__global__ void k_reduce_s(float* __restrict__ sbuf, float* __restrict__ vdst) {
    int b = blockIdx.x, t = threadIdx.x;   // 160 threads: t = n*16+u
    float s = sbuf[(size_t)b * NU + t];
    sbuf[(size_t)b * NU + t] = 0.f;        // self-zero for next k_uhat_s
    __shared__ float sv[NU];
    __shared__ float fb[UU];
    sv[t] = s; __syncthreads();
    if (t < UU) {
        float m = 0.f;
        #pragma unroll
        for (int n = 0; n < NN; ++n) { float z = sv[n*16 + t]; m = fmaf(z, z, m); }
        fb[t] = sqrtf(m) / (1.f + m);   // == (m/(1+m)) / sqrt(m)
    }
    __syncthreads();
    vdst[(size_t)b * NU + t] = s * fb[t & 15];
}

// ---------------- heavy pass 2: db[j*10+n] += <u_hat, v> (atomic) --------
// grid (36 j-tiles of 32, 32 b-tiles of 8), block 320: jl = tid&31, n = tid>>5.
// W row processed in two u-halves: wf[64] live at a time -> no spills.
__global__ void __launch_bounds__(320, 4)
k_uhat_db(const float* __restrict__ xg, const float* __restrict__ wg,
          const float* __restrict__ v, float* __restrict__ db) {
    const int jt = blockIdx.x, bt = blockIdx.y;
    const int j0 = jt * 32, b0 = bt * 8;
    const int tid = threadIdx.x;
    const int jl = tid & 31;
    const int n  = tid >> 5;     // 0..9

    __shared__ float xs2[2048];  // [((i>>2)*8+b)*32 + jl]*4 + (i&3)
    __shared__ float vs2[8 * NU];

    for (int idx = tid; idx < 2048; idx += 320) {
        int jj = idx & 31;
        int r  = idx >> 5;
        int i  = r & 7;
        int b  = r >> 3;
        xs2[(((i >> 2)*8 + b)*32 + jj)*4 + (i & 3)] =
            xg[(size_t)(b0 + b) * (IU*JC) + i * JC + j0 + jj];
    }
    for (int idx = tid; idx < 8*NU; idx += 320)
        vs2[idx] = v[(size_t)b0 * NU + idx];
    __syncthreads();

    const int j = j0 + jl;
    const float* wrow = wg + (size_t)j * WROW + n * (UU*IU);

    float acc = 0.f;
    #pragma unroll
    for (int uh = 0; uh < 2; ++uh) {
        const float4* wp = reinterpret_cast<const float4*>(wrow + uh * 64);
        float wf[64];            // wf[u8*8 + i]
        #pragma unroll
        for (int r = 0; r < 16; ++r) {
            float4 wv = wp[r];
            wf[r*4+0] = wv.x; wf[r*4+1] = wv.y;
            wf[r*4+2] = wv.z; wf[r*4+3] = wv.w;
        }
        #pragma unroll
        for (int b = 0; b < 8; ++b) {
            const float4* xp0 = reinterpret_cast<const float4*>(&xs2[((b)*32 + jl)*4]);
            const float4* xp1 = reinterpret_cast<const float4*>(&xs2[((8 + b)*32 + jl)*4]);
            float4 xa = xp0[0], xb = xp1[0];
            const float4* vp = reinterpret_cast<const float4*>(&vs2[b*NU + n*16 + uh*8]);
            float4 v0 = vp[0], v1 = vp[1];
            float vr[8] = {v0.x,v0.y,v0.z,v0.w, v1.x,v1.y,v1.z,v1.w};
            #pragma unroll
            for (int u = 0; u < 8; ++u) {
                const float* w8 = &wf[u*8];
                float t;
                t = w8[0] * xa.x;
                t = fmaf(w8[1], xa.y, t); t = fmaf(w8[2], xa.z, t);
                t = fmaf(w8[3], xa.w, t); t = fmaf(w8[4], xb.x, t);
                t = fmaf(w8[5], xb.y, t); t = fmaf(w8[6], xb.z, t);
                t = fmaf(w8[7], xb.w, t);
                acc = fmaf(t, vr[u], acc);
            }
        }
    }
    atomicAdd(&db[(size_t)j * NN + n], acc);
}

extern "C" void kernel_launch(void* const* d_in, const int* in_sizes, int n_in,
                              void* d_out, int out_size, void* d_ws, size_t ws_size,
                              hipStream_t stream) {
    const float* x = (const float*)d_in[0];
    const float* w = (const float*)d_in[1];
    float* out = (float*)d_out;    // reference output dtype is float32

    float* ws   = (float*)d_ws;
    float* blog = ws;                 // 11520 floats
    float* c    = blog + JN;          // 11520
    float* sbuf = c + JN;             // 40960
    float* v    = sbuf + (size_t)B*NU;// 40960
    float* db   = v + (size_t)B*NU;   // 11520
    // total: 116480 floats = 465,920 bytes

    hipMemsetAsync(blog, 0, JN * sizeof(float), stream);
    hipMemsetAsync(sbuf, 0, (size_t)B * NU * sizeof(float), stream);
    hipMemsetAsync(db, 0, JN * sizeof(float), stream);

    for (int t = 0; t < 3; ++t) {
        // iter 0: c == softmax(0) == 1/JC exactly -> constant, no softmax launch
        k_uhat_s<<<dim3(36, 32), 320, 0, stream>>>(x, w, (t == 0) ? nullptr : c, sbuf);
        k_reduce_s<<<B, NU, 0, stream>>>(sbuf, (t == 2) ? out : v);
        if (t < 2) {
            k_uhat_db<<<dim3(36, 32), 320, 0, stream>>>(x, w, v, db);
            k_softmax_upd<<<NN, 256, 0, stream>>>(blog, db, c);
        }
    }
}

// Round 7
// 272.234 us; speedup vs baseline: 1.3171x; 1.3171x over previous
//
#include <hip/hip_runtime.h>
#include <stdint.h>

#define B   256
#define IU  8      // in_units (i)
#define JC  1152   // in_channels (j)
#define NN  10     // num_units (n)
#define UU  16     // unit_size (u)
#define NU  160    // NN*UU
#define JN  11520  // JC*NN
#define WROW 1280  // NN*UU*IU, floats per j in W

// ---- fused: blog += db/B; c = softmax_j(blog); db = 0 -------------------
__global__ void k_softmax_upd(float* __restrict__ blog, float* __restrict__ db,
                              float* __restrict__ c) {
    int n = blockIdx.x;           // 0..9
    int tid = threadIdx.x;        // 256
    float myv[5]; int cnt = 0;
    for (int j = tid; j < JC; j += 256) {
        float val = blog[j*NN + n] + db[j*NN + n] * (1.f / (float)B);
        blog[j*NN + n] = val;
        db[j*NN + n] = 0.f;       // self-zero for next k_uhat_db
        myv[cnt++] = val;
    }
    __shared__ float red[256];
    float m = -1e30f;
    for (int k = 0; k < cnt; ++k) m = fmaxf(m, myv[k]);
    red[tid] = m; __syncthreads();
    for (int s = 128; s > 0; s >>= 1) {
        if (tid < s) red[tid] = fmaxf(red[tid], red[tid+s]);
        __syncthreads();
    }
    m = red[0]; __syncthreads();
    float sum = 0.f;
    for (int k = 0; k < cnt; ++k) sum += __expf(myv[k] - m);
    red[tid] = sum; __syncthreads();
    for (int s = 128; s > 0; s >>= 1) {
        if (tid < s) red[tid] += red[tid+s];
        __syncthreads();
    }
    float inv = 1.f / red[0];
    cnt = 0;
    for (int j = tid; j < JC; j += 256)
        c[j*NN + n] = __expf(myv[cnt++] - m) * inv;
}

// ---------------- heavy pass 1: sbuf[b][n*16+u] += c*u_hat ----------------
// grid (36 j-tiles of 32, 32 b-tiles of 8), block 256 (4 waves).
// Wave w handles j's [w*8, w*8+8). Lane = dn*32 + u*2 + ih.
// A wave's 64 lanes load 64 CONSECUTIVE float4s of W (coalesced):
// W[j][np*2+dn][u][ih*4 .. ih*4+4).
__global__ void __launch_bounds__(256, 3)
k_uhat_s(const float* __restrict__ xg, const float* __restrict__ wg,
         const float* __restrict__ cptr, float* __restrict__ sbuf) {
    const int j0 = blockIdx.x * 32, b0 = blockIdx.y * 8;
    const int tid   = threadIdx.x;
    const int wv_id = tid >> 6;
    const int lane  = tid & 63;
    const int dn = lane >> 5;
    const int u  = (lane >> 1) & 15;
    const int ih = lane & 1;

    __shared__ float xs[32 * 68];      // xs[jl*68 + b*8 + i]
    __shared__ float cs[320];          // cs[jl*10 + n]
    __shared__ float red[4 * 32 * 40]; // per-wave partials: 20 KB

    for (int idx = tid; idx < 2048; idx += 256) {
        int jl = idx & 31, r = idx >> 5, i = r & 7, b = r >> 3;
        xs[jl*68 + b*8 + i] = xg[(size_t)(b0 + b) * (IU*JC) + i * JC + j0 + jl];
    }
    if (cptr) for (int idx = tid; idx < 320; idx += 256) cs[idx] = cptr[j0*NN + idx];
    __syncthreads();

    float acc[40];                     // acc[b*5 + np]
    #pragma unroll
    for (int k = 0; k < 40; ++k) acc[k] = 0.f;

    for (int jj = 0; jj < 8; ++jj) {
        const int jl = wv_id * 8 + jj;
        const int j  = j0 + jl;
        const float4* wp = reinterpret_cast<const float4*>(wg + (size_t)j * WROW) + lane;
        float4 wv[5];
        #pragma unroll
        for (int np = 0; np < 5; ++np) wv[np] = wp[np * 64];   // coalesced 1KB/instr
        float cc[5];
        #pragma unroll
        for (int np = 0; np < 5; ++np)
            cc[np] = cptr ? cs[jl*NN + np*2 + dn] : (1.0f / (float)JC);
        float4 xr[8];
        #pragma unroll
        for (int b = 0; b < 8; ++b)
            xr[b] = *reinterpret_cast<const float4*>(&xs[jl*68 + b*8 + ih*4]);

        #pragma unroll
        for (int np = 0; np < 5; ++np) {
            float4 w = wv[np];
            #pragma unroll
            for (int b = 0; b < 8; ++b) {
                float4 xx = xr[b];
                float d = w.x * xx.x;
                d = fmaf(w.y, xx.y, d);
                d = fmaf(w.z, xx.z, d);
                d = fmaf(w.w, xx.w, d);
                d += __shfl_xor(d, 1);               // combine ih halves
                acc[b*5 + np] = fmaf(d, cc[np], acc[b*5 + np]);
            }
        }
    }

    // cross-wave reduce via LDS (ih==0 lanes hold the pair value)
    if (ih == 0) {
        float* dst = &red[(size_t)(wv_id*32 + dn*16 + u) * 40];
        #pragma unroll
        for (int k = 0; k < 40; k += 4) {
            float4 t = make_float4(acc[k], acc[k+1], acc[k+2], acc[k+3]);
            *reinterpret_cast<float4*>(&dst[k]) = t;
        }
    }
    __syncthreads();
    #pragma unroll
    for (int q = 0; q < 5; ++q) {
        int tgt   = tid * 5 + q;     // 0..1279
        int combo = tgt / 40;        // dn*16 + u
        int k     = tgt % 40;        // b*5 + np
        float s = red[(0*32 + combo)*40 + k] + red[(1*32 + combo)*40 + k]
                + red[(2*32 + combo)*40 + k] + red[(3*32 + combo)*40 + k];
        int b = k / 5, np = k % 5;
        int dn2 = combo >> 4, u2 = combo & 15;
        atomicAdd(&sbuf[(size_t)(b0 + b) * NU + (np*2 + dn2)*16 + u2], s);
    }
}

// ---------------- squash: vdst[b][t] = squash(sbuf)[b][t]; sbuf = 0 ------
__global__ void k_reduce_s(float* __restrict__ sbuf, float* __restrict__ vdst) {
    int b = blockIdx.x, t = threadIdx.x;   // 160 threads: t = n*16+u
    float s = sbuf[(size_t)b * NU + t];
    sbuf[(size_t)b * NU + t] = 0.f;        // self-zero for next k_uhat_s
    __shared__ float sv[NU];
    __shared__ float fb[UU];
    sv[t] = s; __syncthreads();
    if (t < UU) {
        float m = 0.f;
        #pragma unroll
        for (int n = 0; n < NN; ++n) { float z = sv[n*16 + t]; m = fmaf(z, z, m); }
        fb[t] = sqrtf(m) / (1.f + m);   // == (m/(1+m)) / sqrt(m)
    }
    __syncthreads();
    vdst[(size_t)b * NU + t] = s * fb[t & 15];
}

// ---------------- heavy pass 2: db[j*10+n] += <u_hat, v> -----------------
// Same lane mapping & coalesced W loads as pass 1; v hoisted to registers;
// u-reduction via 4 xor-shuffles; 320 atomics/block.
__global__ void __launch_bounds__(256, 3)
k_uhat_db(const float* __restrict__ xg, const float* __restrict__ wg,
          const float* __restrict__ v, float* __restrict__ db) {
    const int j0 = blockIdx.x * 32, b0 = blockIdx.y * 8;
    const int tid   = threadIdx.x;
    const int wv_id = tid >> 6;
    const int lane  = tid & 63;
    const int dn = lane >> 5;
    const int u  = (lane >> 1) & 15;
    const int ih = lane & 1;

    __shared__ float xs[32 * 68];
    __shared__ float vs2[8 * NU];

    for (int idx = tid; idx < 2048; idx += 256) {
        int jl = idx & 31, r = idx >> 5, i = r & 7, b = r >> 3;
        xs[jl*68 + b*8 + i] = xg[(size_t)(b0 + b) * (IU*JC) + i * JC + j0 + jl];
    }
    for (int idx = tid; idx < 8*NU; idx += 256)
        vs2[idx] = v[(size_t)b0 * NU + idx];
    __syncthreads();

    float vr[40];                       // vr[b*5 + np] = v[b][np*2+dn][u]
    #pragma unroll
    for (int b = 0; b < 8; ++b)
        #pragma unroll
        for (int np = 0; np < 5; ++np)
            vr[b*5 + np] = vs2[b*NU + (np*2 + dn)*16 + u];

    for (int jj = 0; jj < 8; ++jj) {
        const int jl = wv_id * 8 + jj;
        const int j  = j0 + jl;
        const float4* wp = reinterpret_cast<const float4*>(wg + (size_t)j * WROW) + lane;
        float4 wv[5];
        #pragma unroll
        for (int np = 0; np < 5; ++np) wv[np] = wp[np * 64];
        float4 xr[8];
        #pragma unroll
        for (int b = 0; b < 8; ++b)
            xr[b] = *reinterpret_cast<const float4*>(&xs[jl*68 + b*8 + ih*4]);

        #pragma unroll
        for (int np = 0; np < 5; ++np) {
            float4 w = wv[np];
            float t = 0.f;
            #pragma unroll
            for (int b = 0; b < 8; ++b) {
                float4 xx = xr[b];
                float d = w.x * xx.x;
                d = fmaf(w.y, xx.y, d);
                d = fmaf(w.z, xx.z, d);
                d = fmaf(w.w, xx.w, d);
                d += __shfl_xor(d, 1);               // ih pair
                t = fmaf(d, vr[b*5 + np], t);
            }
            // reduce over the 16 u-lanes (bits 1..4)
            t += __shfl_xor(t, 2);
            t += __shfl_xor(t, 4);
            t += __shfl_xor(t, 8);
            t += __shfl_xor(t, 16);
            if ((lane & 31) == 0)                    // lanes 0 (dn=0), 32 (dn=1)
                atomicAdd(&db[(size_t)j * NN + np*2 + dn], t);
        }
    }
}

extern "C" void kernel_launch(void* const* d_in, const int* in_sizes, int n_in,
                              void* d_out, int out_size, void* d_ws, size_t ws_size,
                              hipStream_t stream) {
    const float* x = (const float*)d_in[0];
    const float* w = (const float*)d_in[1];
    float* out = (float*)d_out;    // reference output dtype is float32

    float* ws   = (float*)d_ws;
    float* blog = ws;                 // 11520 floats
    float* c    = blog + JN;          // 11520
    float* sbuf = c + JN;             // 40960
    float* v    = sbuf + (size_t)B*NU;// 40960
    float* db   = v + (size_t)B*NU;   // 11520
    // total: 116480 floats = 465,920 bytes

    hipMemsetAsync(blog, 0, JN * sizeof(float), stream);
    hipMemsetAsync(sbuf, 0, (size_t)B * NU * sizeof(float), stream);
    hipMemsetAsync(db, 0, JN * sizeof(float), stream);

    for (int t = 0; t < 3; ++t) {
        // iter 0: c == softmax(0) == 1/JC exactly -> constant, no softmax launch
        k_uhat_s<<<dim3(36, 32), 256, 0, stream>>>(x, w, (t == 0) ? nullptr : c, sbuf);
        k_reduce_s<<<B, NU, 0, stream>>>(sbuf, (t == 2) ? out : v);
        if (t < 2) {
            k_uhat_db<<<dim3(36, 32), 256, 0, stream>>>(x, w, v, db);
            k_softmax_upd<<<NN, 256, 0, stream>>>(blog, db, c);
        }
    }
}